// Round 8
// baseline (717.749 us; speedup 1.0000x reference)
//
#include <hip/hip_runtime.h>
#include <hip/hip_bf16.h>

// NodeGCN: GCNConv + 2x GINConv (edge-attr MLPs) + BN + concat + 2-layer head.
// Round 8: edge kernel occupancy x3 (1024-thr/16-wave blocks share one weight
// LDS copy -> 77KB/block, 2 blocks/CU = 32 waves/CU vs 11) + VALU diet
// (packed bf16 converts via v_cvt_pk, bb2 in GEMM2 C-init, msk-fmaf epilogue).
// Node pipeline unchanged from R7 except packed converts.

#define HH 96
#define EDGEF 16
#define CAT (3 * HH)

typedef __attribute__((ext_vector_type(8))) short bf16x8;
typedef __attribute__((ext_vector_type(4))) float f32x4;
typedef __attribute__((ext_vector_type(4))) unsigned short ubf16x4;

typedef union { bf16x8 v; unsigned u[4]; } bfpack8;
typedef union { ubf16x4 v; unsigned u[2]; } bfpack4;

__device__ __forceinline__ unsigned short f2bf(float f) {
    unsigned u = __float_as_uint(f);
    u += 0x7fffu + ((u >> 16) & 1u);      // round-to-nearest-even
    return (unsigned short)(u >> 16);
}
__device__ __forceinline__ float bf2f(unsigned short s) {
    return __uint_as_float(((unsigned)s) << 16);
}
// packed f32x2 -> bf16x2 (RNE, 1 v_cvt_pk_bf16_f32); lo 16 bits = lo input
__device__ __forceinline__ unsigned pkbf2(float lo, float hi) {
    __hip_bfloat162 b = __float22bfloat162_rn(make_float2(lo, hi));
    union { __hip_bfloat162 b2; unsigned u; } cv; cv.b2 = b; return cv.u;
}

// ---------------- unified MFMA node GEMM -----------------------------------------
// C[M,F] = epi(A_eff[M,K] @ W[K,F] + bias)
// AMODE: 0 = f32 A; 1 = bf16 A; 2 = gin-pre (A_eff = (1+eps)*bf16 h + f32 agg)
// EPI:   0 = f32 C; 1 = relu->bf16 C; 2 = relu->BN->bf16 C + dense bf16 copy;
//        3 = f32 C + dense bf16 copy
// Frag mapping (verified R2): A row=lr,k=8lg+j; B col=lr,k=8lg+j; D row=4lg+reg,col=lr.
template <int K, int F, int AMODE, int EPI>
__global__ __launch_bounds__(256) void node_gemm(
    const void* __restrict__ Aptr, int lda,
    const float* __restrict__ agg,
    const float* __restrict__ eps_arr, int li,
    const float* __restrict__ W, const float* __restrict__ bias,
    void* __restrict__ Cptr, int ldc,
    unsigned short* __restrict__ bf_copy,
    const float* __restrict__ gamma, const float* __restrict__ beta,
    const float* __restrict__ mean, const float* __restrict__ var,
    int M)
{
    constexpr int SW = ((K * 2) % 128 == 0) ? 7 : 3;   // XOR span fits row stride
    constexpr int NFT = F / 16;
    __shared__ __align__(16) short s_wt[F * K];        // W^T bf16, XOR-swizzled

    const int tid = threadIdx.x;
    const int lane = tid & 63;
    const int w = tid >> 6;
    const int lr = lane & 15;
    const int lg = lane >> 4;

    for (int idx = tid; idx < F * K; idx += 256) {
        int f = idx / K, k = idx - f * K;
        s_wt[idx ^ ((f & SW) << 3)] = (short)f2bf(W[k * F + f]);
    }
    __syncthreads();

    const int R0 = blockIdx.x * 64 + 16 * w;
    const int Ra = min(R0 + lr, M - 1);

    float e1 = 0.f;
    if (AMODE == 2) e1 = 1.f + eps_arr[li];

    f32x4 acc[NFT];
#pragma unroll
    for (int ft = 0; ft < NFT; ++ft) {
        float b = bias[16 * ft + lr];
        acc[ft][0] = b; acc[ft][1] = b; acc[ft][2] = b; acc[ft][3] = b;
    }

#pragma unroll
    for (int kt = 0; kt < K / 32; ++kt) {
        bf16x8 ae;
        if (AMODE == 0) {
            const float* ap = (const float*)Aptr + (size_t)Ra * lda + 32 * kt + 8 * lg;
            f32x4 a0 = *(const f32x4*)ap;
            f32x4 a1 = *(const f32x4*)(ap + 4);
            bfpack8 p;
            p.u[0] = pkbf2(a0[0], a0[1]); p.u[1] = pkbf2(a0[2], a0[3]);
            p.u[2] = pkbf2(a1[0], a1[1]); p.u[3] = pkbf2(a1[2], a1[3]);
            ae = p.v;
        } else if (AMODE == 1) {
            ae = *(const bf16x8*)((const unsigned short*)Aptr + (size_t)Ra * lda + 32 * kt + 8 * lg);
        } else {
            const unsigned short* hp = (const unsigned short*)Aptr + (size_t)Ra * lda + 32 * kt + 8 * lg;
            bf16x8 h8 = *(const bf16x8*)hp;
            const float* gp = agg + (size_t)Ra * HH + 32 * kt + 8 * lg;
            f32x4 g0 = *(const f32x4*)gp;
            f32x4 g1 = *(const f32x4*)(gp + 4);
            float t0 = fmaf(e1, bf2f((unsigned short)h8[0]), g0[0]);
            float t1 = fmaf(e1, bf2f((unsigned short)h8[1]), g0[1]);
            float t2 = fmaf(e1, bf2f((unsigned short)h8[2]), g0[2]);
            float t3 = fmaf(e1, bf2f((unsigned short)h8[3]), g0[3]);
            float t4 = fmaf(e1, bf2f((unsigned short)h8[4]), g1[0]);
            float t5 = fmaf(e1, bf2f((unsigned short)h8[5]), g1[1]);
            float t6 = fmaf(e1, bf2f((unsigned short)h8[6]), g1[2]);
            float t7 = fmaf(e1, bf2f((unsigned short)h8[7]), g1[3]);
            bfpack8 p;
            p.u[0] = pkbf2(t0, t1); p.u[1] = pkbf2(t2, t3);
            p.u[2] = pkbf2(t4, t5); p.u[3] = pkbf2(t6, t7);
            ae = p.v;
        }
#pragma unroll
        for (int ft = 0; ft < NFT; ++ft) {
            bf16x8 bw = *(const bf16x8*)&s_wt[((lr + 16 * ft) * K + 32 * kt + 8 * lg) ^ ((lr & SW) << 3)];
            acc[ft] = __builtin_amdgcn_mfma_f32_16x16x32_bf16(ae, bw, acc[ft], 0, 0, 0);
        }
    }

    float scale[NFT], shiftv[NFT];
    if (EPI == 2) {
#pragma unroll
        for (int ft = 0; ft < NFT; ++ft) {
            int col = 16 * ft + lr;
            float s = gamma[col] * rsqrtf(var[col] + 1e-5f);
            scale[ft] = s;
            shiftv[ft] = beta[col] - mean[col] * s;
        }
    }
#pragma unroll
    for (int reg = 0; reg < 4; ++reg) {
        int r = R0 + 4 * lg + reg;
        if (r < M) {
#pragma unroll
            for (int ft = 0; ft < NFT; ++ft) {
                int col = 16 * ft + lr;
                float v = acc[ft][reg];
                if (EPI == 0) {
                    ((float*)Cptr)[(size_t)r * ldc + col] = v;
                } else if (EPI == 1) {
                    ((unsigned short*)Cptr)[(size_t)r * ldc + col] = f2bf(fmaxf(v, 0.f));
                } else if (EPI == 2) {
                    float z = fmaxf(v, 0.f) * scale[ft] + shiftv[ft];
                    unsigned short zb = f2bf(z);
                    ((unsigned short*)Cptr)[(size_t)r * ldc + col] = zb;
                    bf_copy[(size_t)r * F + col] = zb;
                } else {
                    ((float*)Cptr)[(size_t)r * ldc + col] = v;
                    bf_copy[(size_t)r * F + col] = f2bf(v);
                }
            }
        }
    }
}

// ---------------- CSR build (fused) ----------------------------------------------
__global__ void init_kernel(float* __restrict__ deg, int* __restrict__ cnt, int N)
{
    int i = blockIdx.x * blockDim.x + threadIdx.x;
    if (i < N) { deg[i] = 1.f; cnt[i] = 0; }
}

__global__ void count_kernel(const int* __restrict__ row, const int* __restrict__ col,
                             float* __restrict__ deg, int* __restrict__ cnt, int E)
{
    int e = blockIdx.x * blockDim.x + threadIdx.x;
    if (e < E) {
        atomicAdd(&deg[row[e]], 1.f);
        atomicAdd(&cnt[col[e]], 1);
    }
}

__global__ void scan1_kernel(const int* __restrict__ cnt, int* __restrict__ start,
                             int* __restrict__ bsum, int N)
{
    __shared__ int s[256];
    int tid = threadIdx.x;
    int i = blockIdx.x * 256 + tid;
    int v = (i < N) ? cnt[i] : 0;
    s[tid] = v;
    __syncthreads();
#pragma unroll
    for (int off = 1; off < 256; off <<= 1) {
        int t = (tid >= off) ? s[tid - off] : 0;
        __syncthreads();
        s[tid] += t;
        __syncthreads();
    }
    if (i < N) start[i] = s[tid] - v;
    if (tid == 255) bsum[blockIdx.x] = s[255];
}

__global__ void scan2_kernel(int* __restrict__ bsum, int nb)
{
    __shared__ int s[256];
    int tid = threadIdx.x;
    int v = (tid < nb) ? bsum[tid] : 0;
    s[tid] = v;
    __syncthreads();
#pragma unroll
    for (int off = 1; off < 256; off <<= 1) {
        int t = (tid >= off) ? s[tid - off] : 0;
        __syncthreads();
        s[tid] += t;
        __syncthreads();
    }
    if (tid < nb) bsum[tid] = s[tid] - v;
}

__global__ void scan3_kernel(int* __restrict__ start, const int* __restrict__ bsum,
                             int* __restrict__ cursor,
                             const float* __restrict__ deg, float* __restrict__ dinv,
                             int N, int E)
{
    int i = blockIdx.x * blockDim.x + threadIdx.x;
    if (i < N) {
        int f = start[i] + bsum[i >> 8];
        start[i] = f;
        cursor[i] = f;
        dinv[i] = rsqrtf(deg[i]);
    } else if (i == N) {
        start[N] = E;
    }
}

// scatter + edge_attr permute+cvt fused
__global__ void scatter_ea_kernel(const int* __restrict__ row, const int* __restrict__ col,
                                  int* __restrict__ cursor,
                                  const float* __restrict__ ea,
                                  int* __restrict__ row_sorted,
                                  unsigned short* __restrict__ eas, int E)
{
    int e = blockIdx.x * blockDim.x + threadIdx.x;
    if (e >= E) return;
    int c = col[e];
    int p = atomicAdd(&cursor[c], 1);
    row_sorted[p] = row[e];
    const float* src = ea + (size_t)e * EDGEF;
    f32x4 v0 = *(const f32x4*)(src);
    f32x4 v1 = *(const f32x4*)(src + 4);
    f32x4 v2 = *(const f32x4*)(src + 8);
    f32x4 v3 = *(const f32x4*)(src + 12);
    bfpack8 o0, o1;
    o0.u[0] = pkbf2(v0[0], v0[1]); o0.u[1] = pkbf2(v0[2], v0[3]);
    o0.u[2] = pkbf2(v1[0], v1[1]); o0.u[3] = pkbf2(v1[2], v1[3]);
    o1.u[0] = pkbf2(v2[0], v2[1]); o1.u[1] = pkbf2(v2[2], v2[3]);
    o1.u[2] = pkbf2(v3[0], v3[1]); o1.u[3] = pkbf2(v3[2], v3[3]);
    *(bf16x8*)(eas + (size_t)p * EDGEF) = o0.v;
    *(bf16x8*)(eas + (size_t)p * EDGEF + 8) = o1.v;
}

// ---------------- node-centric MFMA edge kernel ----------------------------------
// 16 waves/block (one shared weight-LDS copy -> 77KB, 2 blocks/CU = 32 waves/CU).
// One wave per destination node; per 16-edge batch: h rows prefetched whole,
// parked in the freed s_t wave slice; packed bf16 converts; bb2 in C-init;
// msk-fmaf accumulate. MFMA fragment layouts as verified in R2.
template <bool GCN>
__global__ __launch_bounds__(1024, 8) void edge_kernel(
    const unsigned short* __restrict__ ea_sorted,
    const int* __restrict__ row_sorted,
    const int* __restrict__ seg_start,
    const float* __restrict__ bw1, const float* __restrict__ bb1,
    const float* __restrict__ bw2, const float* __restrict__ bb2,
    const unsigned short* __restrict__ hbf,
    const float* __restrict__ dinv,
    float* __restrict__ agg,
    int N)
{
    __shared__ __align__(16) short s_bw2T[96][104];   // bw2^T bf16 [f][k] 19968B
    __shared__ __align__(16) short s_bw1T[96][16];    // bw1^T bf16 [f][k]  3072B
    __shared__ __align__(16) short s_t[16][16][104];  // per-wave t / h park 53248B
    __shared__ float s_bias[192];                     // bb1 | bb2            768B

    const int tid = threadIdx.x;
    const int lane = tid & 63;
    const int w = tid >> 6;          // wave 0..15
    const int lr = lane & 15;
    const int lg = lane >> 4;

    for (int idx = tid; idx < HH * HH; idx += 1024) {
        int k = idx / HH, f = idx - k * HH;
        s_bw2T[f][k] = (short)f2bf(bw2[idx]);
    }
    for (int idx = tid; idx < EDGEF * HH; idx += 1024) {
        int k = idx / HH, f = idx - k * HH;
        s_bw1T[f][k] = (short)f2bf(bw1[idx]);
    }
    if (tid < HH) { s_bias[tid] = bb1[tid]; s_bias[HH + tid] = bb2[tid]; }
    __syncthreads();

    const f32x4 zf = {0.f, 0.f, 0.f, 0.f};
    const int nwaves = gridDim.x * 16;

    for (int c = blockIdx.x * 16 + w; c < N; c += nwaves) {
        const int s0 = seg_start[c];
        const int s1 = seg_start[c + 1];
        float dinv_c = GCN ? dinv[c] : 1.f;

        f32x4 acc[6];
#pragma unroll
        for (int ft = 0; ft < 6; ++ft) acc[ft] = zf;

        for (int b = s0; b < s1; b += 16) {
            const int epos = b + lr;
            const bool vld = (epos < s1);
            const int epc = vld ? epos : s0;
            const int r = row_sorted[epc];

            // prefetch full h row (lane (lr,lg) covers 48B chunk lg of row lr)
            const unsigned short* hrow = hbf + (size_t)r * HH + 24 * lg;
            bf16x8 h0 = *(const bf16x8*)(hrow);
            bf16x8 h1 = *(const bf16x8*)(hrow + 8);
            bf16x8 h2 = *(const bf16x8*)(hrow + 16);

            const float msk = vld ? (GCN ? dinv[r] * dinv_c : 1.f) : 0.f;

            // A-frag: sequential 16B bf16 load (k<16 real, rest zero)
            bf16x8 ae;
#pragma unroll
            for (int j = 0; j < 8; ++j) ae[j] = 0;
            if (lg < 2)
                ae = *(const bf16x8*)(ea_sorted + (size_t)epc * EDGEF + 8 * lg);

            // GEMM1 + bias + relu -> s_t (t layout [edge][feat]), packed cvt
#pragma unroll
            for (int ft = 0; ft < 6; ++ft) {
                bf16x8 b1;
#pragma unroll
                for (int j = 0; j < 8; ++j) b1[j] = 0;
                if (lg < 2)
                    b1 = *(const bf16x8*)&s_bw1T[lr + 16 * ft][8 * lg];
                f32x4 tacc = __builtin_amdgcn_mfma_f32_16x16x32_bf16(ae, b1, zf, 0, 0, 0);
                float bsv = s_bias[lr + 16 * ft];
                float v0 = fmaxf(tacc[0] + bsv, 0.f);
                float v1 = fmaxf(tacc[1] + bsv, 0.f);
                float v2 = fmaxf(tacc[2] + bsv, 0.f);
                float v3 = fmaxf(tacc[3] + bsv, 0.f);
                unsigned u01 = pkbf2(v0, v1);
                unsigned u23 = pkbf2(v2, v3);
                const int colf = lr + 16 * ft;
                s_t[w][4 * lg + 0][colf] = (short)u01;
                s_t[w][4 * lg + 1][colf] = (short)(u01 >> 16);
                s_t[w][4 * lg + 2][colf] = (short)u23;
                s_t[w][4 * lg + 3][colf] = (short)(u23 >> 16);
            }
            __builtin_amdgcn_wave_barrier();    // t writes before bt reads

            // GEMM2 B-frags: t^T, col=edge=lr
            bf16x8 bt[3];
#pragma unroll
            for (int kt = 0; kt < 3; ++kt)
                bt[kt] = *(const bf16x8*)&s_t[w][lr][8 * lg + 32 * kt];
            __builtin_amdgcn_wave_barrier();    // bt reads before h overwrites

            // park h rows in the freed slice (lane (lr,lg) -> row lr, chunk lg)
            *(bf16x8*)&s_t[w][lr][24 * lg]      = h0;
            *(bf16x8*)&s_t[w][lr][24 * lg + 8]  = h1;
            *(bf16x8*)&s_t[w][lr][24 * lg + 16] = h2;
            __builtin_amdgcn_wave_barrier();    // h writes before hv reads

            // GEMM2 (swapped, bb2 in C-init) + epilogue
#pragma unroll
            for (int ft = 0; ft < 6; ++ft) {
                const int fb = 16 * ft + 4 * lg;
                f32x4 ee = *(const f32x4*)&s_bias[HH + fb];
#pragma unroll
                for (int kt = 0; kt < 3; ++kt) {
                    bf16x8 aw = *(const bf16x8*)&s_bw2T[lr + 16 * ft][8 * lg + 32 * kt];
                    ee = __builtin_amdgcn_mfma_f32_16x16x32_bf16(aw, bt[kt], ee, 0, 0, 0);
                }
                ubf16x4 hv = *(const ubf16x4*)&s_t[w][lr][fb];
#pragma unroll
                for (int reg = 0; reg < 4; ++reg) {
                    float m = fmaxf(bf2f(hv[reg]) + ee[reg], 0.f);
                    acc[ft][reg] = fmaf(m, msk, acc[ft][reg]);
                }
            }
        }

        // reduce over the 16-edge lane dimension
#pragma unroll
        for (int ft = 0; ft < 6; ++ft) {
#pragma unroll
            for (int reg = 0; reg < 4; ++reg) {
                float v = acc[ft][reg];
                v += __shfl_xor(v, 1);
                v += __shfl_xor(v, 2);
                v += __shfl_xor(v, 4);
                v += __shfl_xor(v, 8);
                acc[ft][reg] = v;
            }
        }
        if (lr == 0) {
#pragma unroll
            for (int ft = 0; ft < 6; ++ft)
                *(f32x4*)&agg[(size_t)c * HH + 16 * ft + 4 * lg] = acc[ft];
        }
    }
}

// ---------------- GCN epilogue (f32 agg+self -> BN -> bf16 feats + dense hb) -----
__global__ void gcn_epilogue_kernel(
    const float* __restrict__ agg, const float* __restrict__ hbuf,
    const float* __restrict__ root, const float* __restrict__ deg,
    const float* __restrict__ gamma, const float* __restrict__ beta,
    const float* __restrict__ mean, const float* __restrict__ var,
    unsigned short* __restrict__ featsbf, unsigned short* __restrict__ hb, int N)
{
    int idx = blockIdx.x * blockDim.x + threadIdx.x;   // quad index
    if (idx >= N * (HH / 4)) return;
    int n = idx / (HH / 4), q = idx - n * (HH / 4);
    int f0 = 4 * q;
    f32x4 a  = *(const f32x4*)&agg[(size_t)n * HH + f0];
    f32x4 h  = *(const f32x4*)&hbuf[(size_t)n * HH + f0];
    f32x4 rt = *(const f32x4*)&root[f0];
    f32x4 gm = *(const f32x4*)&gamma[f0];
    f32x4 bt = *(const f32x4*)&beta[f0];
    f32x4 mn = *(const f32x4*)&mean[f0];
    f32x4 vr = *(const f32x4*)&var[f0];
    float di = 1.f / deg[n];
    float vv[4];
#pragma unroll
    for (int j = 0; j < 4; ++j) {
        float self = fmaxf(h[j] + rt[j], 0.f) * di;
        float v = fmaxf(a[j] + self, 0.f);
        vv[j] = (v - mn[j]) * rsqrtf(vr[j] + 1e-5f) * gm[j] + bt[j];
    }
    bfpack4 o;
    o.u[0] = pkbf2(vv[0], vv[1]);
    o.u[1] = pkbf2(vv[2], vv[3]);
    *(ubf16x4*)&featsbf[(size_t)n * CAT + f0] = o.v;
    *(ubf16x4*)&hb[(size_t)n * HH + f0] = o.v;
}

// ---------------- launch ----------------------------------------------------------
extern "C" void kernel_launch(void* const* d_in, const int* in_sizes, int n_in,
                              void* d_out, int out_size, void* d_ws, size_t ws_size,
                              hipStream_t stream)
{
    const float* x         = (const float*)d_in[0];
    const int*   eidx      = (const int*)d_in[1];
    const float* edge_attr = (const float*)d_in[2];
    const float* gcn_lin_w = (const float*)d_in[3];
    const float* gcn_lin_b = (const float*)d_in[4];
    const float* gcn_root  = (const float*)d_in[5];
    const float* gcn_bw1   = (const float*)d_in[6];
    const float* gcn_bb1   = (const float*)d_in[7];
    const float* gcn_bw2   = (const float*)d_in[8];
    const float* gcn_bb2   = (const float*)d_in[9];
    const float* gin_bw1   = (const float*)d_in[10];
    const float* gin_bb1   = (const float*)d_in[11];
    const float* gin_bw2   = (const float*)d_in[12];
    const float* gin_bb2   = (const float*)d_in[13];
    const float* gin_mw1   = (const float*)d_in[14];
    const float* gin_mb1   = (const float*)d_in[15];
    const float* gin_mw2   = (const float*)d_in[16];
    const float* gin_mb2   = (const float*)d_in[17];
    const float* gin_eps   = (const float*)d_in[18];
    const float* bn_gamma  = (const float*)d_in[19];
    const float* bn_beta   = (const float*)d_in[20];
    const float* bn_mean   = (const float*)d_in[21];
    const float* bn_var    = (const float*)d_in[22];
    const float* fc1_w     = (const float*)d_in[23];
    const float* fc1_b     = (const float*)d_in[24];
    const float* fc2_w     = (const float*)d_in[25];
    const float* fc2_b     = (const float*)d_in[26];
    float* out = (float*)d_out;

    const int N = in_sizes[0] / 128;   // 50000
    const int E = in_sizes[1] / 2;     // 800000
    const int* row = eidx;
    const int* col = eidx + E;

    // ws layout (bytes)
    char* ws = (char*)d_ws;
    float* deg        = (float*)(ws);                          // N f32
    float* dinv       = (float*)(ws + (size_t)256 * 1024);     // N f32
    int*   seg_start  = (int*)(ws + (size_t)512 * 1024);       // N+1
    int*   cursor     = (int*)(ws + (size_t)768 * 1024);       // N (also hist cnt)
    int*   bsum       = (int*)(ws + (size_t)1024 * 1024);      // 256
    int*   row_sorted = (int*)(ws + (size_t)1088 * 1024);      // E (3.2MB)
    unsigned short* ea_sorted = (unsigned short*)(ws + (size_t)8 * 1024 * 1024);    // E*16 bf16
    unsigned short* hb        = (unsigned short*)(ws + (size_t)34 * 1024 * 1024);   // N*96 bf16
    float* hbuf   = (float*)(ws + (size_t)44 * 1024 * 1024);   // N*96 f32
    float* agg    = (float*)(ws + (size_t)64 * 1024 * 1024);   // N*96 f32
    unsigned short* featsbf = (unsigned short*)(ws + (size_t)84 * 1024 * 1024);     // N*288 bf16
    unsigned short* z1bf    = (unsigned short*)(ws + (size_t)113 * 1024 * 1024);    // N*96 bf16
    unsigned short* r1bf    = (unsigned short*)(ws + (size_t)123 * 1024 * 1024);    // N*96 bf16

    const int ew_blocks = 512;                      // 2 blocks/CU x 256 CU, 16 waves each
    const int q_grid = (N * (HH / 4) + 255) / 256;
    const int gemm_grid = (N + 63) / 64;
    const int e_grid = (E + 255) / 256;
    const int n_grid = (N + 255) / 256;
    const int nchunks = (N + 255) / 256;

    // ---- degrees + CSR build ----
    init_kernel<<<n_grid, 256, 0, stream>>>(deg, cursor, N);
    count_kernel<<<e_grid, 256, 0, stream>>>(row, col, deg, cursor, E);
    scan1_kernel<<<nchunks, 256, 0, stream>>>(cursor, seg_start, bsum, N);
    scan2_kernel<<<1, 256, 0, stream>>>(bsum, nchunks);
    scan3_kernel<<<(N + 256) / 256, 256, 0, stream>>>(seg_start, bsum, cursor, deg, dinv, N, E);
    scatter_ea_kernel<<<e_grid, 256, 0, stream>>>(row, col, cursor, edge_attr,
                                                  row_sorted, ea_sorted, E);

    // ---- layer 0: GCN ----
    node_gemm<128, 96, 0, 3><<<gemm_grid, 256, 0, stream>>>(
        x, 128, nullptr, nullptr, 0, gcn_lin_w, gcn_lin_b,
        hbuf, HH, hb, nullptr, nullptr, nullptr, nullptr, N);
    edge_kernel<true><<<ew_blocks, 1024, 0, stream>>>(
        ea_sorted, row_sorted, seg_start,
        gcn_bw1, gcn_bb1, gcn_bw2, gcn_bb2, hb, dinv, agg, N);
    gcn_epilogue_kernel<<<q_grid, 256, 0, stream>>>(
        agg, hbuf, gcn_root, deg, bn_gamma, bn_beta, bn_mean, bn_var, featsbf, hb, N);

    // ---- layers 1..2: GIN ----
    for (int i = 0; i < 2; ++i) {
        edge_kernel<false><<<ew_blocks, 1024, 0, stream>>>(
            ea_sorted, row_sorted, seg_start,
            gin_bw1 + (size_t)i * EDGEF * HH, gin_bb1 + i * HH,
            gin_bw2 + (size_t)i * HH * HH, gin_bb2 + i * HH,
            hb, dinv, agg, N);
        // z1 = relu((1+eps)*h + agg) @ mw1 + mb1  -> bf16 (h read dense from hb)
        node_gemm<96, 96, 2, 1><<<gemm_grid, 256, 0, stream>>>(
            hb, HH, agg, gin_eps, i,
            gin_mw1 + (size_t)i * HH * HH, gin_mb1 + i * HH,
            z1bf, HH, nullptr, nullptr, nullptr, nullptr, nullptr, N);
        // feats[i+1] = BN(relu(z1 @ mw2 + mb2)) -> strided featsbf + dense hb
        node_gemm<96, 96, 1, 2><<<gemm_grid, 256, 0, stream>>>(
            z1bf, HH, nullptr, nullptr, 0,
            gin_mw2 + (size_t)i * HH * HH, gin_mb2 + i * HH,
            featsbf + (i + 1) * HH, CAT, hb,
            bn_gamma + (i + 1) * HH, bn_beta + (i + 1) * HH,
            bn_mean + (i + 1) * HH, bn_var + (i + 1) * HH, N);
    }

    // ---- head ----
    node_gemm<288, 96, 1, 1><<<gemm_grid, 256, 0, stream>>>(
        featsbf, CAT, nullptr, nullptr, 0, fc1_w, fc1_b,
        r1bf, HH, nullptr, nullptr, nullptr, nullptr, nullptr, N);
    node_gemm<96, 64, 1, 0><<<gemm_grid, 256, 0, stream>>>(
        r1bf, HH, nullptr, nullptr, 0, fc2_w, fc2_b,
        out, 64, nullptr, nullptr, nullptr, nullptr, nullptr, N);
}

// Round 9
// 676.079 us; speedup vs baseline: 1.0616x; 1.0616x over previous
//
#include <hip/hip_runtime.h>
#include <hip/hip_bf16.h>

// NodeGCN: GCNConv + 2x GINConv (edge-attr MLPs) + BN + concat + 2-layer head.
// Round 9: edge kernel instruction/chain diet at the proven (256,4) shape:
// (1) GEMM1 operand swap -> D = t^T, lane owns 4 consecutive feats of edge lr:
//     pk pairs -> 6x ds_write_b64 (was 24 scattered b16), bt reads unchanged;
// (2) bw1 A-frags hoisted to persistent regs (zero for k>=16) -> ae needs no
//     zero/branch; (3) bb1 via MFMA C-init. Node pipeline unchanged from R8.

#define HH 96
#define EDGEF 16
#define CAT (3 * HH)

typedef __attribute__((ext_vector_type(8))) short bf16x8;
typedef __attribute__((ext_vector_type(4))) float f32x4;
typedef __attribute__((ext_vector_type(4))) unsigned short ubf16x4;
typedef __attribute__((ext_vector_type(2))) unsigned uint2v;

typedef union { bf16x8 v; unsigned u[4]; } bfpack8;
typedef union { ubf16x4 v; unsigned u[2]; } bfpack4;

__device__ __forceinline__ unsigned short f2bf(float f) {
    unsigned u = __float_as_uint(f);
    u += 0x7fffu + ((u >> 16) & 1u);      // round-to-nearest-even
    return (unsigned short)(u >> 16);
}
__device__ __forceinline__ float bf2f(unsigned short s) {
    return __uint_as_float(((unsigned)s) << 16);
}
// packed f32x2 -> bf16x2 (RNE, v_cvt_pk_bf16_f32); lo 16 bits = lo input
__device__ __forceinline__ unsigned pkbf2(float lo, float hi) {
    __hip_bfloat162 b = __float22bfloat162_rn(make_float2(lo, hi));
    union { __hip_bfloat162 b2; unsigned u; } cv; cv.b2 = b; return cv.u;
}

// ---------------- unified MFMA node GEMM -----------------------------------------
// C[M,F] = epi(A_eff[M,K] @ W[K,F] + bias)
// AMODE: 0 = f32 A; 1 = bf16 A; 2 = gin-pre (A_eff = (1+eps)*bf16 h + f32 agg)
// EPI:   0 = f32 C; 1 = relu->bf16 C; 2 = relu->BN->bf16 C + dense bf16 copy;
//        3 = f32 C + dense bf16 copy
// Frag mapping (verified R2): A row=lr,k=8lg+j; B col=lr,k=8lg+j; D row=4lg+reg,col=lr.
template <int K, int F, int AMODE, int EPI>
__global__ __launch_bounds__(256) void node_gemm(
    const void* __restrict__ Aptr, int lda,
    const float* __restrict__ agg,
    const float* __restrict__ eps_arr, int li,
    const float* __restrict__ W, const float* __restrict__ bias,
    void* __restrict__ Cptr, int ldc,
    unsigned short* __restrict__ bf_copy,
    const float* __restrict__ gamma, const float* __restrict__ beta,
    const float* __restrict__ mean, const float* __restrict__ var,
    int M)
{
    constexpr int SW = ((K * 2) % 128 == 0) ? 7 : 3;   // XOR span fits row stride
    constexpr int NFT = F / 16;
    __shared__ __align__(16) short s_wt[F * K];        // W^T bf16, XOR-swizzled

    const int tid = threadIdx.x;
    const int lane = tid & 63;
    const int w = tid >> 6;
    const int lr = lane & 15;
    const int lg = lane >> 4;

    for (int idx = tid; idx < F * K; idx += 256) {
        int f = idx / K, k = idx - f * K;
        s_wt[idx ^ ((f & SW) << 3)] = (short)f2bf(W[k * F + f]);
    }
    __syncthreads();

    const int R0 = blockIdx.x * 64 + 16 * w;
    const int Ra = min(R0 + lr, M - 1);

    float e1 = 0.f;
    if (AMODE == 2) e1 = 1.f + eps_arr[li];

    f32x4 acc[NFT];
#pragma unroll
    for (int ft = 0; ft < NFT; ++ft) {
        float b = bias[16 * ft + lr];
        acc[ft][0] = b; acc[ft][1] = b; acc[ft][2] = b; acc[ft][3] = b;
    }

#pragma unroll
    for (int kt = 0; kt < K / 32; ++kt) {
        bf16x8 ae;
        if (AMODE == 0) {
            const float* ap = (const float*)Aptr + (size_t)Ra * lda + 32 * kt + 8 * lg;
            f32x4 a0 = *(const f32x4*)ap;
            f32x4 a1 = *(const f32x4*)(ap + 4);
            bfpack8 p;
            p.u[0] = pkbf2(a0[0], a0[1]); p.u[1] = pkbf2(a0[2], a0[3]);
            p.u[2] = pkbf2(a1[0], a1[1]); p.u[3] = pkbf2(a1[2], a1[3]);
            ae = p.v;
        } else if (AMODE == 1) {
            ae = *(const bf16x8*)((const unsigned short*)Aptr + (size_t)Ra * lda + 32 * kt + 8 * lg);
        } else {
            const unsigned short* hp = (const unsigned short*)Aptr + (size_t)Ra * lda + 32 * kt + 8 * lg;
            bf16x8 h8 = *(const bf16x8*)hp;
            const float* gp = agg + (size_t)Ra * HH + 32 * kt + 8 * lg;
            f32x4 g0 = *(const f32x4*)gp;
            f32x4 g1 = *(const f32x4*)(gp + 4);
            float t0 = fmaf(e1, bf2f((unsigned short)h8[0]), g0[0]);
            float t1 = fmaf(e1, bf2f((unsigned short)h8[1]), g0[1]);
            float t2 = fmaf(e1, bf2f((unsigned short)h8[2]), g0[2]);
            float t3 = fmaf(e1, bf2f((unsigned short)h8[3]), g0[3]);
            float t4 = fmaf(e1, bf2f((unsigned short)h8[4]), g1[0]);
            float t5 = fmaf(e1, bf2f((unsigned short)h8[5]), g1[1]);
            float t6 = fmaf(e1, bf2f((unsigned short)h8[6]), g1[2]);
            float t7 = fmaf(e1, bf2f((unsigned short)h8[7]), g1[3]);
            bfpack8 p;
            p.u[0] = pkbf2(t0, t1); p.u[1] = pkbf2(t2, t3);
            p.u[2] = pkbf2(t4, t5); p.u[3] = pkbf2(t6, t7);
            ae = p.v;
        }
#pragma unroll
        for (int ft = 0; ft < NFT; ++ft) {
            bf16x8 bw = *(const bf16x8*)&s_wt[((lr + 16 * ft) * K + 32 * kt + 8 * lg) ^ ((lr & SW) << 3)];
            acc[ft] = __builtin_amdgcn_mfma_f32_16x16x32_bf16(ae, bw, acc[ft], 0, 0, 0);
        }
    }

    float scale[NFT], shiftv[NFT];
    if (EPI == 2) {
#pragma unroll
        for (int ft = 0; ft < NFT; ++ft) {
            int col = 16 * ft + lr;
            float s = gamma[col] * rsqrtf(var[col] + 1e-5f);
            scale[ft] = s;
            shiftv[ft] = beta[col] - mean[col] * s;
        }
    }
#pragma unroll
    for (int reg = 0; reg < 4; ++reg) {
        int r = R0 + 4 * lg + reg;
        if (r < M) {
#pragma unroll
            for (int ft = 0; ft < NFT; ++ft) {
                int col = 16 * ft + lr;
                float v = acc[ft][reg];
                if (EPI == 0) {
                    ((float*)Cptr)[(size_t)r * ldc + col] = v;
                } else if (EPI == 1) {
                    ((unsigned short*)Cptr)[(size_t)r * ldc + col] = f2bf(fmaxf(v, 0.f));
                } else if (EPI == 2) {
                    float z = fmaxf(v, 0.f) * scale[ft] + shiftv[ft];
                    unsigned short zb = f2bf(z);
                    ((unsigned short*)Cptr)[(size_t)r * ldc + col] = zb;
                    bf_copy[(size_t)r * F + col] = zb;
                } else {
                    ((float*)Cptr)[(size_t)r * ldc + col] = v;
                    bf_copy[(size_t)r * F + col] = f2bf(v);
                }
            }
        }
    }
}

// ---------------- CSR build (fused) ----------------------------------------------
__global__ void init_kernel(float* __restrict__ deg, int* __restrict__ cnt, int N)
{
    int i = blockIdx.x * blockDim.x + threadIdx.x;
    if (i < N) { deg[i] = 1.f; cnt[i] = 0; }
}

__global__ void count_kernel(const int* __restrict__ row, const int* __restrict__ col,
                             float* __restrict__ deg, int* __restrict__ cnt, int E)
{
    int e = blockIdx.x * blockDim.x + threadIdx.x;
    if (e < E) {
        atomicAdd(&deg[row[e]], 1.f);
        atomicAdd(&cnt[col[e]], 1);
    }
}

__global__ void scan1_kernel(const int* __restrict__ cnt, int* __restrict__ start,
                             int* __restrict__ bsum, int N)
{
    __shared__ int s[256];
    int tid = threadIdx.x;
    int i = blockIdx.x * 256 + tid;
    int v = (i < N) ? cnt[i] : 0;
    s[tid] = v;
    __syncthreads();
#pragma unroll
    for (int off = 1; off < 256; off <<= 1) {
        int t = (tid >= off) ? s[tid - off] : 0;
        __syncthreads();
        s[tid] += t;
        __syncthreads();
    }
    if (i < N) start[i] = s[tid] - v;
    if (tid == 255) bsum[blockIdx.x] = s[255];
}

__global__ void scan2_kernel(int* __restrict__ bsum, int nb)
{
    __shared__ int s[256];
    int tid = threadIdx.x;
    int v = (tid < nb) ? bsum[tid] : 0;
    s[tid] = v;
    __syncthreads();
#pragma unroll
    for (int off = 1; off < 256; off <<= 1) {
        int t = (tid >= off) ? s[tid - off] : 0;
        __syncthreads();
        s[tid] += t;
        __syncthreads();
    }
    if (tid < nb) bsum[tid] = s[tid] - v;
}

__global__ void scan3_kernel(int* __restrict__ start, const int* __restrict__ bsum,
                             int* __restrict__ cursor,
                             const float* __restrict__ deg, float* __restrict__ dinv,
                             int N, int E)
{
    int i = blockIdx.x * blockDim.x + threadIdx.x;
    if (i < N) {
        int f = start[i] + bsum[i >> 8];
        start[i] = f;
        cursor[i] = f;
        dinv[i] = rsqrtf(deg[i]);
    } else if (i == N) {
        start[N] = E;
    }
}

// scatter + edge_attr permute+cvt fused
__global__ void scatter_ea_kernel(const int* __restrict__ row, const int* __restrict__ col,
                                  int* __restrict__ cursor,
                                  const float* __restrict__ ea,
                                  int* __restrict__ row_sorted,
                                  unsigned short* __restrict__ eas, int E)
{
    int e = blockIdx.x * blockDim.x + threadIdx.x;
    if (e >= E) return;
    int c = col[e];
    int p = atomicAdd(&cursor[c], 1);
    row_sorted[p] = row[e];
    const float* src = ea + (size_t)e * EDGEF;
    f32x4 v0 = *(const f32x4*)(src);
    f32x4 v1 = *(const f32x4*)(src + 4);
    f32x4 v2 = *(const f32x4*)(src + 8);
    f32x4 v3 = *(const f32x4*)(src + 12);
    bfpack8 o0, o1;
    o0.u[0] = pkbf2(v0[0], v0[1]); o0.u[1] = pkbf2(v0[2], v0[3]);
    o0.u[2] = pkbf2(v1[0], v1[1]); o0.u[3] = pkbf2(v1[2], v1[3]);
    o1.u[0] = pkbf2(v2[0], v2[1]); o1.u[1] = pkbf2(v2[2], v2[3]);
    o1.u[2] = pkbf2(v3[0], v3[1]); o1.u[3] = pkbf2(v3[2], v3[3]);
    *(bf16x8*)(eas + (size_t)p * EDGEF) = o0.v;
    *(bf16x8*)(eas + (size_t)p * EDGEF + 8) = o1.v;
}

// ---------------- node-centric MFMA edge kernel ----------------------------------
// One wave per destination node, (256,4), 37.4KB LDS (proven R5/R7 shape).
// GEMM1 operands SWAPPED: t4 = mfma(bwf, ae, ci) -> D = t^T, lane holds
// t[edge=lr][feat=16ft+4lg+reg] -> pk pairs -> ds_write_b64 x6 (edge-major s_t,
// bt reads unchanged). bwf persistent regs (zero k>=16) -> ae branch-free.
template <bool GCN>
__global__ __launch_bounds__(256, 4) void edge_kernel(
    const unsigned short* __restrict__ ea_sorted,
    const int* __restrict__ row_sorted,
    const int* __restrict__ seg_start,
    const float* __restrict__ bw1, const float* __restrict__ bb1,
    const float* __restrict__ bw2, const float* __restrict__ bb2,
    const unsigned short* __restrict__ hbf,
    const float* __restrict__ dinv,
    float* __restrict__ agg,
    int N)
{
    __shared__ __align__(16) short s_bw2T[96][104];   // bw2^T bf16 [f][k] 19968B
    __shared__ __align__(16) short s_bw1T[96][16];    // bw1^T bf16 [f][k]  3072B
    __shared__ __align__(16) short s_t[4][16][104];   // per-wave t / h park 13312B
    __shared__ float s_bias[192];                     // bb1 | bb2            768B

    const int tid = threadIdx.x;
    const int lane = tid & 63;
    const int w = tid >> 6;
    const int lr = lane & 15;
    const int lg = lane >> 4;

    for (int idx = tid; idx < HH * HH; idx += 256) {
        int k = idx / HH, f = idx - k * HH;
        s_bw2T[f][k] = (short)f2bf(bw2[idx]);
    }
    for (int idx = tid; idx < EDGEF * HH; idx += 256) {
        int k = idx / HH, f = idx - k * HH;
        s_bw1T[f][k] = (short)f2bf(bw1[idx]);
    }
    if (tid < HH) { s_bias[tid] = bb1[tid]; s_bias[HH + tid] = bb2[tid]; }
    __syncthreads();

    // persistent bw1^T A-frags: A[row=lr+16ft][k=8lg+j]; zero for k>=16 (lg>=2)
    bf16x8 bwf[6];
#pragma unroll
    for (int ft = 0; ft < 6; ++ft) {
        bf16x8 z;
#pragma unroll
        for (int j = 0; j < 8; ++j) z[j] = 0;
        if (lg < 2) z = *(const bf16x8*)&s_bw1T[lr + 16 * ft][8 * lg];
        bwf[ft] = z;
    }

    const int nwaves = gridDim.x * 4;

    for (int c = blockIdx.x * 4 + w; c < N; c += nwaves) {
        const int s0 = seg_start[c];
        const int s1 = seg_start[c + 1];
        const float dinv_c = GCN ? dinv[c] : 1.f;

        f32x4 acc[6];
#pragma unroll
        for (int ft = 0; ft < 6; ++ft) { acc[ft][0]=0.f; acc[ft][1]=0.f; acc[ft][2]=0.f; acc[ft][3]=0.f; }

        for (int b = s0; b < s1; b += 16) {
            const int epos = b + lr;
            const bool vld = (epos < s1);
            const int epc = vld ? epos : s0;
            const int r = row_sorted[epc];

            // prefetch full h row (lane (lr,lg) covers 48B chunk lg of row lr)
            const unsigned short* hrow = hbf + (size_t)r * HH + 24 * lg;
            bf16x8 h0 = *(const bf16x8*)(hrow);
            bf16x8 h1 = *(const bf16x8*)(hrow + 8);
            bf16x8 h2 = *(const bf16x8*)(hrow + 16);

            const float msk = vld ? (GCN ? dinv[r] * dinv_c : 1.f) : 0.f;

            // B-frag (ea^T): B[k=8lg+j][col=edge lr]; k>=16 garbage x zero A = 0
            bf16x8 ae = *(const bf16x8*)(ea_sorted + (size_t)epc * EDGEF + 8 * (lg & 1));

            // GEMM1 swapped: D = t^T (row=feat 4lg+reg, col=edge lr), bb1 in C-init
#pragma unroll
            for (int ft = 0; ft < 6; ++ft) {
                f32x4 ci = *(const f32x4*)&s_bias[16 * ft + 4 * lg];
                f32x4 t4 = __builtin_amdgcn_mfma_f32_16x16x32_bf16(bwf[ft], ae, ci, 0, 0, 0);
                float v0 = fmaxf(t4[0], 0.f);
                float v1 = fmaxf(t4[1], 0.f);
                float v2 = fmaxf(t4[2], 0.f);
                float v3 = fmaxf(t4[3], 0.f);
                uint2v uu;
                uu[0] = pkbf2(v0, v1);
                uu[1] = pkbf2(v2, v3);
                *(uint2v*)&s_t[w][lr][16 * ft + 4 * lg] = uu;   // 8B store, 8B-aligned
            }
            __builtin_amdgcn_wave_barrier();    // t writes before bt reads

            // GEMM2 B-frags: t[edge=lr][k=8lg+j+32kt]
            bf16x8 bt[3];
#pragma unroll
            for (int kt = 0; kt < 3; ++kt)
                bt[kt] = *(const bf16x8*)&s_t[w][lr][8 * lg + 32 * kt];
            __builtin_amdgcn_wave_barrier();    // bt reads before h overwrites

            // park h rows in the freed slice (lane (lr,lg) -> row lr, chunk lg)
            *(bf16x8*)&s_t[w][lr][24 * lg]      = h0;
            *(bf16x8*)&s_t[w][lr][24 * lg + 8]  = h1;
            *(bf16x8*)&s_t[w][lr][24 * lg + 16] = h2;
            __builtin_amdgcn_wave_barrier();    // h writes before hv reads

            // GEMM2 (swapped, bb2 in C-init) + epilogue
#pragma unroll
            for (int ft = 0; ft < 6; ++ft) {
                const int fb = 16 * ft + 4 * lg;
                f32x4 ee = *(const f32x4*)&s_bias[HH + fb];
#pragma unroll
                for (int kt = 0; kt < 3; ++kt) {
                    bf16x8 aw = *(const bf16x8*)&s_bw2T[lr + 16 * ft][8 * lg + 32 * kt];
                    ee = __builtin_amdgcn_mfma_f32_16x16x32_bf16(aw, bt[kt], ee, 0, 0, 0);
                }
                ubf16x4 hv = *(const ubf16x4*)&s_t[w][lr][fb];
#pragma unroll
                for (int reg = 0; reg < 4; ++reg) {
                    float m = fmaxf(bf2f(hv[reg]) + ee[reg], 0.f);
                    acc[ft][reg] = fmaf(m, msk, acc[ft][reg]);
                }
            }
        }

        // reduce over the 16-edge lane dimension
#pragma unroll
        for (int ft = 0; ft < 6; ++ft) {
#pragma unroll
            for (int reg = 0; reg < 4; ++reg) {
                float v = acc[ft][reg];
                v += __shfl_xor(v, 1);
                v += __shfl_xor(v, 2);
                v += __shfl_xor(v, 4);
                v += __shfl_xor(v, 8);
                acc[ft][reg] = v;
            }
        }
        if (lr == 0) {
#pragma unroll
            for (int ft = 0; ft < 6; ++ft)
                *(f32x4*)&agg[(size_t)c * HH + 16 * ft + 4 * lg] = acc[ft];
        }
    }
}

// ---------------- GCN epilogue (f32 agg+self -> BN -> bf16 feats + dense hb) -----
__global__ void gcn_epilogue_kernel(
    const float* __restrict__ agg, const float* __restrict__ hbuf,
    const float* __restrict__ root, const float* __restrict__ deg,
    const float* __restrict__ gamma, const float* __restrict__ beta,
    const float* __restrict__ mean, const float* __restrict__ var,
    unsigned short* __restrict__ featsbf, unsigned short* __restrict__ hb, int N)
{
    int idx = blockIdx.x * blockDim.x + threadIdx.x;   // quad index
    if (idx >= N * (HH / 4)) return;
    int n = idx / (HH / 4), q = idx - n * (HH / 4);
    int f0 = 4 * q;
    f32x4 a  = *(const f32x4*)&agg[(size_t)n * HH + f0];
    f32x4 h  = *(const f32x4*)&hbuf[(size_t)n * HH + f0];
    f32x4 rt = *(const f32x4*)&root[f0];
    f32x4 gm = *(const f32x4*)&gamma[f0];
    f32x4 bt = *(const f32x4*)&beta[f0];
    f32x4 mn = *(const f32x4*)&mean[f0];
    f32x4 vr = *(const f32x4*)&var[f0];
    float di = 1.f / deg[n];
    float vv[4];
#pragma unroll
    for (int j = 0; j < 4; ++j) {
        float self = fmaxf(h[j] + rt[j], 0.f) * di;
        float v = fmaxf(a[j] + self, 0.f);
        vv[j] = (v - mn[j]) * rsqrtf(vr[j] + 1e-5f) * gm[j] + bt[j];
    }
    bfpack4 o;
    o.u[0] = pkbf2(vv[0], vv[1]);
    o.u[1] = pkbf2(vv[2], vv[3]);
    *(ubf16x4*)&featsbf[(size_t)n * CAT + f0] = o.v;
    *(ubf16x4*)&hb[(size_t)n * HH + f0] = o.v;
}

// ---------------- launch ----------------------------------------------------------
extern "C" void kernel_launch(void* const* d_in, const int* in_sizes, int n_in,
                              void* d_out, int out_size, void* d_ws, size_t ws_size,
                              hipStream_t stream)
{
    const float* x         = (const float*)d_in[0];
    const int*   eidx      = (const int*)d_in[1];
    const float* edge_attr = (const float*)d_in[2];
    const float* gcn_lin_w = (const float*)d_in[3];
    const float* gcn_lin_b = (const float*)d_in[4];
    const float* gcn_root  = (const float*)d_in[5];
    const float* gcn_bw1   = (const float*)d_in[6];
    const float* gcn_bb1   = (const float*)d_in[7];
    const float* gcn_bw2   = (const float*)d_in[8];
    const float* gcn_bb2   = (const float*)d_in[9];
    const float* gin_bw1   = (const float*)d_in[10];
    const float* gin_bb1   = (const float*)d_in[11];
    const float* gin_bw2   = (const float*)d_in[12];
    const float* gin_bb2   = (const float*)d_in[13];
    const float* gin_mw1   = (const float*)d_in[14];
    const float* gin_mb1   = (const float*)d_in[15];
    const float* gin_mw2   = (const float*)d_in[16];
    const float* gin_mb2   = (const float*)d_in[17];
    const float* gin_eps   = (const float*)d_in[18];
    const float* bn_gamma  = (const float*)d_in[19];
    const float* bn_beta   = (const float*)d_in[20];
    const float* bn_mean   = (const float*)d_in[21];
    const float* bn_var    = (const float*)d_in[22];
    const float* fc1_w     = (const float*)d_in[23];
    const float* fc1_b     = (const float*)d_in[24];
    const float* fc2_w     = (const float*)d_in[25];
    const float* fc2_b     = (const float*)d_in[26];
    float* out = (float*)d_out;

    const int N = in_sizes[0] / 128;   // 50000
    const int E = in_sizes[1] / 2;     // 800000
    const int* row = eidx;
    const int* col = eidx + E;

    // ws layout (bytes)
    char* ws = (char*)d_ws;
    float* deg        = (float*)(ws);                          // N f32
    float* dinv       = (float*)(ws + (size_t)256 * 1024);     // N f32
    int*   seg_start  = (int*)(ws + (size_t)512 * 1024);       // N+1
    int*   cursor     = (int*)(ws + (size_t)768 * 1024);       // N (also hist cnt)
    int*   bsum       = (int*)(ws + (size_t)1024 * 1024);      // 256
    int*   row_sorted = (int*)(ws + (size_t)1088 * 1024);      // E (3.2MB)
    unsigned short* ea_sorted = (unsigned short*)(ws + (size_t)8 * 1024 * 1024);    // E*16 bf16
    unsigned short* hb        = (unsigned short*)(ws + (size_t)34 * 1024 * 1024);   // N*96 bf16
    float* hbuf   = (float*)(ws + (size_t)44 * 1024 * 1024);   // N*96 f32
    float* agg    = (float*)(ws + (size_t)64 * 1024 * 1024);   // N*96 f32
    unsigned short* featsbf = (unsigned short*)(ws + (size_t)84 * 1024 * 1024);     // N*288 bf16
    unsigned short* z1bf    = (unsigned short*)(ws + (size_t)113 * 1024 * 1024);    // N*96 bf16
    unsigned short* r1bf    = (unsigned short*)(ws + (size_t)123 * 1024 * 1024);    // N*96 bf16

    const int ew_blocks = 1024;                     // 4 blocks/CU x 256 CU
    const int q_grid = (N * (HH / 4) + 255) / 256;
    const int gemm_grid = (N + 63) / 64;
    const int e_grid = (E + 255) / 256;
    const int n_grid = (N + 255) / 256;
    const int nchunks = (N + 255) / 256;

    // ---- degrees + CSR build ----
    init_kernel<<<n_grid, 256, 0, stream>>>(deg, cursor, N);
    count_kernel<<<e_grid, 256, 0, stream>>>(row, col, deg, cursor, E);
    scan1_kernel<<<nchunks, 256, 0, stream>>>(cursor, seg_start, bsum, N);
    scan2_kernel<<<1, 256, 0, stream>>>(bsum, nchunks);
    scan3_kernel<<<(N + 256) / 256, 256, 0, stream>>>(seg_start, bsum, cursor, deg, dinv, N, E);
    scatter_ea_kernel<<<e_grid, 256, 0, stream>>>(row, col, cursor, edge_attr,
                                                  row_sorted, ea_sorted, E);

    // ---- layer 0: GCN ----
    node_gemm<128, 96, 0, 3><<<gemm_grid, 256, 0, stream>>>(
        x, 128, nullptr, nullptr, 0, gcn_lin_w, gcn_lin_b,
        hbuf, HH, hb, nullptr, nullptr, nullptr, nullptr, N);
    edge_kernel<true><<<ew_blocks, 256, 0, stream>>>(
        ea_sorted, row_sorted, seg_start,
        gcn_bw1, gcn_bb1, gcn_bw2, gcn_bb2, hb, dinv, agg, N);
    gcn_epilogue_kernel<<<q_grid, 256, 0, stream>>>(
        agg, hbuf, gcn_root, deg, bn_gamma, bn_beta, bn_mean, bn_var, featsbf, hb, N);

    // ---- layers 1..2: GIN ----
    for (int i = 0; i < 2; ++i) {
        edge_kernel<false><<<ew_blocks, 256, 0, stream>>>(
            ea_sorted, row_sorted, seg_start,
            gin_bw1 + (size_t)i * EDGEF * HH, gin_bb1 + i * HH,
            gin_bw2 + (size_t)i * HH * HH, gin_bb2 + i * HH,
            hb, dinv, agg, N);
        // z1 = relu((1+eps)*h + agg) @ mw1 + mb1  -> bf16 (h read dense from hb)
        node_gemm<96, 96, 2, 1><<<gemm_grid, 256, 0, stream>>>(
            hb, HH, agg, gin_eps, i,
            gin_mw1 + (size_t)i * HH * HH, gin_mb1 + i * HH,
            z1bf, HH, nullptr, nullptr, nullptr, nullptr, nullptr, N);
        // feats[i+1] = BN(relu(z1 @ mw2 + mb2)) -> strided featsbf + dense hb
        node_gemm<96, 96, 1, 2><<<gemm_grid, 256, 0, stream>>>(
            z1bf, HH, nullptr, nullptr, 0,
            gin_mw2 + (size_t)i * HH * HH, gin_mb2 + i * HH,
            featsbf + (i + 1) * HH, CAT, hb,
            bn_gamma + (i + 1) * HH, bn_beta + (i + 1) * HH,
            bn_mean + (i + 1) * HH, bn_var + (i + 1) * HH, N);
    }

    // ---- head ----
    node_gemm<288, 96, 1, 1><<<gemm_grid, 256, 0, stream>>>(
        featsbf, CAT, nullptr, nullptr, 0, fc1_w, fc1_b,
        r1bf, HH, nullptr, nullptr, nullptr, nullptr, nullptr, N);
    node_gemm<96, 64, 1, 0><<<gemm_grid, 256, 0, stream>>>(
        r1bf, HH, nullptr, nullptr, 0, fc2_w, fc2_b,
        out, 64, nullptr, nullptr, nullptr, nullptr, nullptr, N);
}

// Round 10
// 595.709 us; speedup vs baseline: 1.2049x; 1.1349x over previous
//
#include <hip/hip_runtime.h>
#include <hip/hip_bf16.h>

// NodeGCN: GCNConv + 2x GINConv (edge-attr MLPs) + BN + concat + 2-layer head.
// Round 10: (1) edge kernel: h gathered directly into epilogue lanes (6x8B,
// exact (lr,lg) ownership) -> h-park LDS writes/reads + 2 wave_barriers deleted,
// chain shortened; (2) GIN MLP pair fused into one kernel (swapped GEMM1 ->
// LDS exchange -> GEMM2 -> BN), killing 2 launches + z1 roundtrips per layer.

#define HH 96
#define EDGEF 16
#define CAT (3 * HH)

typedef __attribute__((ext_vector_type(8))) short bf16x8;
typedef __attribute__((ext_vector_type(4))) float f32x4;
typedef __attribute__((ext_vector_type(4))) unsigned short ubf16x4;
typedef __attribute__((ext_vector_type(2))) unsigned uint2v;

typedef union { bf16x8 v; unsigned u[4]; } bfpack8;
typedef union { ubf16x4 v; unsigned u[2]; } bfpack4;

__device__ __forceinline__ unsigned short f2bf(float f) {
    unsigned u = __float_as_uint(f);
    u += 0x7fffu + ((u >> 16) & 1u);      // round-to-nearest-even
    return (unsigned short)(u >> 16);
}
__device__ __forceinline__ float bf2f(unsigned short s) {
    return __uint_as_float(((unsigned)s) << 16);
}
// packed f32x2 -> bf16x2 (RNE, v_cvt_pk_bf16_f32); lo 16 bits = lo input
__device__ __forceinline__ unsigned pkbf2(float lo, float hi) {
    __hip_bfloat162 b = __float22bfloat162_rn(make_float2(lo, hi));
    union { __hip_bfloat162 b2; unsigned u; } cv; cv.b2 = b; return cv.u;
}

// ---------------- unified MFMA node GEMM (layer0 / head) --------------------------
// AMODE: 0 = f32 A; 1 = bf16 A.  EPI: 0 = f32 C; 1 = relu->bf16 C; 3 = f32 C + bf16 copy
template <int K, int F, int AMODE, int EPI>
__global__ __launch_bounds__(256) void node_gemm(
    const void* __restrict__ Aptr, int lda,
    const float* __restrict__ W, const float* __restrict__ bias,
    void* __restrict__ Cptr, int ldc,
    unsigned short* __restrict__ bf_copy,
    int M)
{
    constexpr int SW = ((K * 2) % 128 == 0) ? 7 : 3;
    constexpr int NFT = F / 16;
    __shared__ __align__(16) short s_wt[F * K];

    const int tid = threadIdx.x;
    const int lane = tid & 63;
    const int w = tid >> 6;
    const int lr = lane & 15;
    const int lg = lane >> 4;

    for (int idx = tid; idx < F * K; idx += 256) {
        int f = idx / K, k = idx - f * K;
        s_wt[idx ^ ((f & SW) << 3)] = (short)f2bf(W[k * F + f]);
    }
    __syncthreads();

    const int R0 = blockIdx.x * 64 + 16 * w;
    const int Ra = min(R0 + lr, M - 1);

    f32x4 acc[NFT];
#pragma unroll
    for (int ft = 0; ft < NFT; ++ft) {
        float b = bias[16 * ft + lr];
        acc[ft][0] = b; acc[ft][1] = b; acc[ft][2] = b; acc[ft][3] = b;
    }

#pragma unroll
    for (int kt = 0; kt < K / 32; ++kt) {
        bf16x8 ae;
        if (AMODE == 0) {
            const float* ap = (const float*)Aptr + (size_t)Ra * lda + 32 * kt + 8 * lg;
            f32x4 a0 = *(const f32x4*)ap;
            f32x4 a1 = *(const f32x4*)(ap + 4);
            bfpack8 p;
            p.u[0] = pkbf2(a0[0], a0[1]); p.u[1] = pkbf2(a0[2], a0[3]);
            p.u[2] = pkbf2(a1[0], a1[1]); p.u[3] = pkbf2(a1[2], a1[3]);
            ae = p.v;
        } else {
            ae = *(const bf16x8*)((const unsigned short*)Aptr + (size_t)Ra * lda + 32 * kt + 8 * lg);
        }
#pragma unroll
        for (int ft = 0; ft < NFT; ++ft) {
            bf16x8 bw = *(const bf16x8*)&s_wt[((lr + 16 * ft) * K + 32 * kt + 8 * lg) ^ ((lr & SW) << 3)];
            acc[ft] = __builtin_amdgcn_mfma_f32_16x16x32_bf16(ae, bw, acc[ft], 0, 0, 0);
        }
    }

#pragma unroll
    for (int reg = 0; reg < 4; ++reg) {
        int r = R0 + 4 * lg + reg;
        if (r < M) {
#pragma unroll
            for (int ft = 0; ft < NFT; ++ft) {
                int col = 16 * ft + lr;
                float v = acc[ft][reg];
                if (EPI == 0) {
                    ((float*)Cptr)[(size_t)r * ldc + col] = v;
                } else if (EPI == 1) {
                    ((unsigned short*)Cptr)[(size_t)r * ldc + col] = f2bf(fmaxf(v, 0.f));
                } else {
                    ((float*)Cptr)[(size_t)r * ldc + col] = v;
                    bf_copy[(size_t)r * F + col] = f2bf(v);
                }
            }
        }
    }
}

// ---------------- fused GIN MLP: z=(1+eps)h+agg; out=BN(relu(relu(z@W1+b1)@W2+b2)) --
// GEMM1 swapped (A=W1^T, B=z^T) -> D=z1^T, lane owns 4 consecutive feats of node lr
// -> pk -> ds_write_b64 -> LDS exchange -> GEMM2 normal (A=z1 rows, B=W2) -> BN.
__global__ __launch_bounds__(256) void gin_mlp(
    const unsigned short* __restrict__ hb_in,   // dense [N][96] bf16
    const float* __restrict__ agg,              // dense [N][96] f32
    const float* __restrict__ eps_arr, int li,
    const float* __restrict__ mw1, const float* __restrict__ mb1,
    const float* __restrict__ mw2, const float* __restrict__ mb2,
    const float* __restrict__ gamma, const float* __restrict__ beta,
    const float* __restrict__ mean, const float* __restrict__ var,
    unsigned short* __restrict__ featsbf, int slot,
    unsigned short* __restrict__ hb_out,
    int M)
{
    __shared__ __align__(16) short s_w1t[96][104];   // mw1^T bf16 [f][k] 19968B
    __shared__ __align__(16) short s_w2t[96][104];   // mw2^T bf16 [f][k] 19968B
    __shared__ __align__(16) short s_z[4][16][104];  // per-wave z1 tile   13312B
    __shared__ float s_b[192];                       // mb1 | mb2

    const int tid = threadIdx.x;
    const int lane = tid & 63;
    const int w = tid >> 6;
    const int lr = lane & 15;
    const int lg = lane >> 4;

    for (int idx = tid; idx < HH * HH; idx += 256) {
        int k = idx / HH, f = idx - k * HH;
        s_w1t[f][k] = (short)f2bf(mw1[idx]);
        s_w2t[f][k] = (short)f2bf(mw2[idx]);
    }
    if (tid < HH) { s_b[tid] = mb1[tid]; s_b[HH + tid] = mb2[tid]; }
    __syncthreads();

    const int R0 = blockIdx.x * 64 + 16 * w;
    const int Ra = min(R0 + lr, M - 1);
    const float e1 = 1.f + eps_arr[li];

    // input B-frags (z^T): lane (lr,lg) holds z[row Ra(lr)][k=32kt+8lg+j]
    bf16x8 inf[3];
#pragma unroll
    for (int kt = 0; kt < 3; ++kt) {
        const unsigned short* hp = hb_in + (size_t)Ra * HH + 32 * kt + 8 * lg;
        bf16x8 h8 = *(const bf16x8*)hp;
        const float* gp = agg + (size_t)Ra * HH + 32 * kt + 8 * lg;
        f32x4 g0 = *(const f32x4*)gp;
        f32x4 g1 = *(const f32x4*)(gp + 4);
        float t0 = fmaf(e1, bf2f((unsigned short)h8[0]), g0[0]);
        float t1 = fmaf(e1, bf2f((unsigned short)h8[1]), g0[1]);
        float t2 = fmaf(e1, bf2f((unsigned short)h8[2]), g0[2]);
        float t3 = fmaf(e1, bf2f((unsigned short)h8[3]), g0[3]);
        float t4 = fmaf(e1, bf2f((unsigned short)h8[4]), g1[0]);
        float t5 = fmaf(e1, bf2f((unsigned short)h8[5]), g1[1]);
        float t6 = fmaf(e1, bf2f((unsigned short)h8[6]), g1[2]);
        float t7 = fmaf(e1, bf2f((unsigned short)h8[7]), g1[3]);
        bfpack8 p;
        p.u[0] = pkbf2(t0, t1); p.u[1] = pkbf2(t2, t3);
        p.u[2] = pkbf2(t4, t5); p.u[3] = pkbf2(t6, t7);
        inf[kt] = p.v;
    }

    // GEMM1 swapped: D = z1^T (row=feat 16ft+4lg+reg, col=node lr), mb1 C-init
#pragma unroll
    for (int ft = 0; ft < 6; ++ft) {
        f32x4 t4v = *(const f32x4*)&s_b[16 * ft + 4 * lg];
#pragma unroll
        for (int kt = 0; kt < 3; ++kt) {
            bf16x8 aw = *(const bf16x8*)&s_w1t[16 * ft + lr][32 * kt + 8 * lg];
            t4v = __builtin_amdgcn_mfma_f32_16x16x32_bf16(aw, inf[kt], t4v, 0, 0, 0);
        }
        uint2v uu;
        uu[0] = pkbf2(fmaxf(t4v[0], 0.f), fmaxf(t4v[1], 0.f));
        uu[1] = pkbf2(fmaxf(t4v[2], 0.f), fmaxf(t4v[3], 0.f));
        *(uint2v*)&s_z[w][lr][16 * ft + 4 * lg] = uu;
    }
    __builtin_amdgcn_wave_barrier();

    // GEMM2 normal: A = z1 rows (from s_z), B = mw2 (from s_w2t), mb2 C-init
    bf16x8 az[3];
#pragma unroll
    for (int kt = 0; kt < 3; ++kt)
        az[kt] = *(const bf16x8*)&s_z[w][lr][32 * kt + 8 * lg];

    f32x4 acc[6];
#pragma unroll
    for (int ft = 0; ft < 6; ++ft) {
        float b = s_b[HH + 16 * ft + lr];
        acc[ft][0] = b; acc[ft][1] = b; acc[ft][2] = b; acc[ft][3] = b;
#pragma unroll
        for (int kt = 0; kt < 3; ++kt) {
            bf16x8 bw = *(const bf16x8*)&s_w2t[16 * ft + lr][32 * kt + 8 * lg];
            acc[ft] = __builtin_amdgcn_mfma_f32_16x16x32_bf16(az[kt], bw, acc[ft], 0, 0, 0);
        }
    }

    // epilogue: BN(relu(.)) -> strided featsbf + dense hb_out
    float scale[6], shiftv[6];
#pragma unroll
    for (int ft = 0; ft < 6; ++ft) {
        int col = 16 * ft + lr;
        float s = gamma[col] * rsqrtf(var[col] + 1e-5f);
        scale[ft] = s;
        shiftv[ft] = beta[col] - mean[col] * s;
    }
#pragma unroll
    for (int reg = 0; reg < 4; ++reg) {
        int r = R0 + 4 * lg + reg;
        if (r < M) {
#pragma unroll
            for (int ft = 0; ft < 6; ++ft) {
                int col = 16 * ft + lr;
                float z = fmaxf(acc[ft][reg], 0.f) * scale[ft] + shiftv[ft];
                unsigned short zb = f2bf(z);
                featsbf[(size_t)r * CAT + slot * HH + col] = zb;
                hb_out[(size_t)r * HH + col] = zb;
            }
        }
    }
}

// ---------------- CSR build (fused) ----------------------------------------------
__global__ void init_kernel(float* __restrict__ deg, int* __restrict__ cnt, int N)
{
    int i = blockIdx.x * blockDim.x + threadIdx.x;
    if (i < N) { deg[i] = 1.f; cnt[i] = 0; }
}

__global__ void count_kernel(const int* __restrict__ row, const int* __restrict__ col,
                             float* __restrict__ deg, int* __restrict__ cnt, int E)
{
    int e = blockIdx.x * blockDim.x + threadIdx.x;
    if (e < E) {
        atomicAdd(&deg[row[e]], 1.f);
        atomicAdd(&cnt[col[e]], 1);
    }
}

__global__ void scan1_kernel(const int* __restrict__ cnt, int* __restrict__ start,
                             int* __restrict__ bsum, int N)
{
    __shared__ int s[256];
    int tid = threadIdx.x;
    int i = blockIdx.x * 256 + tid;
    int v = (i < N) ? cnt[i] : 0;
    s[tid] = v;
    __syncthreads();
#pragma unroll
    for (int off = 1; off < 256; off <<= 1) {
        int t = (tid >= off) ? s[tid - off] : 0;
        __syncthreads();
        s[tid] += t;
        __syncthreads();
    }
    if (i < N) start[i] = s[tid] - v;
    if (tid == 255) bsum[blockIdx.x] = s[255];
}

__global__ void scan2_kernel(int* __restrict__ bsum, int nb)
{
    __shared__ int s[256];
    int tid = threadIdx.x;
    int v = (tid < nb) ? bsum[tid] : 0;
    s[tid] = v;
    __syncthreads();
#pragma unroll
    for (int off = 1; off < 256; off <<= 1) {
        int t = (tid >= off) ? s[tid - off] : 0;
        __syncthreads();
        s[tid] += t;
        __syncthreads();
    }
    if (tid < nb) bsum[tid] = s[tid] - v;
}

__global__ void scan3_kernel(int* __restrict__ start, const int* __restrict__ bsum,
                             int* __restrict__ cursor,
                             const float* __restrict__ deg, float* __restrict__ dinv,
                             int N, int E)
{
    int i = blockIdx.x * blockDim.x + threadIdx.x;
    if (i < N) {
        int f = start[i] + bsum[i >> 8];
        start[i] = f;
        cursor[i] = f;
        dinv[i] = rsqrtf(deg[i]);
    } else if (i == N) {
        start[N] = E;
    }
}

// scatter + edge_attr permute+cvt fused
__global__ void scatter_ea_kernel(const int* __restrict__ row, const int* __restrict__ col,
                                  int* __restrict__ cursor,
                                  const float* __restrict__ ea,
                                  int* __restrict__ row_sorted,
                                  unsigned short* __restrict__ eas, int E)
{
    int e = blockIdx.x * blockDim.x + threadIdx.x;
    if (e >= E) return;
    int c = col[e];
    int p = atomicAdd(&cursor[c], 1);
    row_sorted[p] = row[e];
    const float* src = ea + (size_t)e * EDGEF;
    f32x4 v0 = *(const f32x4*)(src);
    f32x4 v1 = *(const f32x4*)(src + 4);
    f32x4 v2 = *(const f32x4*)(src + 8);
    f32x4 v3 = *(const f32x4*)(src + 12);
    bfpack8 o0, o1;
    o0.u[0] = pkbf2(v0[0], v0[1]); o0.u[1] = pkbf2(v0[2], v0[3]);
    o0.u[2] = pkbf2(v1[0], v1[1]); o0.u[3] = pkbf2(v1[2], v1[3]);
    o1.u[0] = pkbf2(v2[0], v2[1]); o1.u[1] = pkbf2(v2[2], v2[3]);
    o1.u[2] = pkbf2(v3[0], v3[1]); o1.u[3] = pkbf2(v3[2], v3[3]);
    *(bf16x8*)(eas + (size_t)p * EDGEF) = o0.v;
    *(bf16x8*)(eas + (size_t)p * EDGEF + 8) = o1.v;
}

// ---------------- node-centric MFMA edge kernel ----------------------------------
// One wave per destination node, (256,4). Per 16-edge batch: h gathered DIRECTLY
// into the lanes that consume it (6x8B at r*96+16ft+4lg), no LDS park, one
// wave_barrier. GEMM1 swapped (R9), b64 t-exchange, bb1/bb2 via MFMA C-init.
template <bool GCN>
__global__ __launch_bounds__(256, 4) void edge_kernel(
    const unsigned short* __restrict__ ea_sorted,
    const int* __restrict__ row_sorted,
    const int* __restrict__ seg_start,
    const float* __restrict__ bw1, const float* __restrict__ bb1,
    const float* __restrict__ bw2, const float* __restrict__ bb2,
    const unsigned short* __restrict__ hbf,
    const float* __restrict__ dinv,
    float* __restrict__ agg,
    int N)
{
    __shared__ __align__(16) short s_bw2T[96][104];   // bw2^T bf16 [f][k] 19968B
    __shared__ __align__(16) short s_bw1T[96][16];    // bw1^T bf16 [f][k]  3072B
    __shared__ __align__(16) short s_t[4][16][104];   // per-wave t tile   13312B
    __shared__ float s_bias[192];                     // bb1 | bb2            768B

    const int tid = threadIdx.x;
    const int lane = tid & 63;
    const int w = tid >> 6;
    const int lr = lane & 15;
    const int lg = lane >> 4;

    for (int idx = tid; idx < HH * HH; idx += 256) {
        int k = idx / HH, f = idx - k * HH;
        s_bw2T[f][k] = (short)f2bf(bw2[idx]);
    }
    for (int idx = tid; idx < EDGEF * HH; idx += 256) {
        int k = idx / HH, f = idx - k * HH;
        s_bw1T[f][k] = (short)f2bf(bw1[idx]);
    }
    if (tid < HH) { s_bias[tid] = bb1[tid]; s_bias[HH + tid] = bb2[tid]; }
    __syncthreads();

    // persistent bw1^T A-frags (zero for k>=16, lg>=2)
    bf16x8 bwf[6];
#pragma unroll
    for (int ft = 0; ft < 6; ++ft) {
        bf16x8 z;
#pragma unroll
        for (int j = 0; j < 8; ++j) z[j] = 0;
        if (lg < 2) z = *(const bf16x8*)&s_bw1T[lr + 16 * ft][8 * lg];
        bwf[ft] = z;
    }

    const int nwaves = gridDim.x * 4;

    for (int c = blockIdx.x * 4 + w; c < N; c += nwaves) {
        const int s0 = seg_start[c];
        const int s1 = seg_start[c + 1];
        const float dinv_c = GCN ? dinv[c] : 1.f;

        f32x4 acc[6];
#pragma unroll
        for (int ft = 0; ft < 6; ++ft) { acc[ft][0]=0.f; acc[ft][1]=0.f; acc[ft][2]=0.f; acc[ft][3]=0.f; }

        for (int b = s0; b < s1; b += 16) {
            const int epos = b + lr;
            const bool vld = (epos < s1);
            const int epc = vld ? epos : s0;
            const int r = row_sorted[epc];

            // direct h gather into epilogue lanes: lane (lr,lg) owns feats 16ft+4lg..+3
            const unsigned short* hrow = hbf + (size_t)r * HH + 4 * lg;
            ubf16x4 hv[6];
#pragma unroll
            for (int ft = 0; ft < 6; ++ft)
                hv[ft] = *(const ubf16x4*)(hrow + 16 * ft);

            const float msk = vld ? (GCN ? dinv[r] * dinv_c : 1.f) : 0.f;

            // B-frag (ea^T): k>=16 garbage x zero A = 0
            bf16x8 ae = *(const bf16x8*)(ea_sorted + (size_t)epc * EDGEF + 8 * (lg & 1));

            // GEMM1 swapped: D = t^T (row=feat 16ft+4lg+reg, col=edge lr), bb1 C-init
#pragma unroll
            for (int ft = 0; ft < 6; ++ft) {
                f32x4 ci = *(const f32x4*)&s_bias[16 * ft + 4 * lg];
                f32x4 t4 = __builtin_amdgcn_mfma_f32_16x16x32_bf16(bwf[ft], ae, ci, 0, 0, 0);
                uint2v uu;
                uu[0] = pkbf2(fmaxf(t4[0], 0.f), fmaxf(t4[1], 0.f));
                uu[1] = pkbf2(fmaxf(t4[2], 0.f), fmaxf(t4[3], 0.f));
                *(uint2v*)&s_t[w][lr][16 * ft + 4 * lg] = uu;
            }
            __builtin_amdgcn_wave_barrier();    // t writes before bt reads

            // GEMM2 B-frags: t[edge=lr][k=8lg+j+32kt]
            bf16x8 bt[3];
#pragma unroll
            for (int kt = 0; kt < 3; ++kt)
                bt[kt] = *(const bf16x8*)&s_t[w][lr][8 * lg + 32 * kt];

            // GEMM2 (swapped, bb2 C-init) + epilogue from registers
#pragma unroll
            for (int ft = 0; ft < 6; ++ft) {
                const int fb = 16 * ft + 4 * lg;
                f32x4 ee = *(const f32x4*)&s_bias[HH + fb];
#pragma unroll
                for (int kt = 0; kt < 3; ++kt) {
                    bf16x8 aw = *(const bf16x8*)&s_bw2T[lr + 16 * ft][8 * lg + 32 * kt];
                    ee = __builtin_amdgcn_mfma_f32_16x16x32_bf16(aw, bt[kt], ee, 0, 0, 0);
                }
#pragma unroll
                for (int reg = 0; reg < 4; ++reg) {
                    float m = fmaxf(bf2f(hv[ft][reg]) + ee[reg], 0.f);
                    acc[ft][reg] = fmaf(m, msk, acc[ft][reg]);
                }
            }
        }

        // reduce over the 16-edge lane dimension
#pragma unroll
        for (int ft = 0; ft < 6; ++ft) {
#pragma unroll
            for (int reg = 0; reg < 4; ++reg) {
                float v = acc[ft][reg];
                v += __shfl_xor(v, 1);
                v += __shfl_xor(v, 2);
                v += __shfl_xor(v, 4);
                v += __shfl_xor(v, 8);
                acc[ft][reg] = v;
            }
        }
        if (lr == 0) {
#pragma unroll
            for (int ft = 0; ft < 6; ++ft)
                *(f32x4*)&agg[(size_t)c * HH + 16 * ft + 4 * lg] = acc[ft];
        }
    }
}

// ---------------- GCN epilogue (f32 agg+self -> BN -> bf16 feats + dense hb) -----
__global__ void gcn_epilogue_kernel(
    const float* __restrict__ agg, const float* __restrict__ hbuf,
    const float* __restrict__ root, const float* __restrict__ deg,
    const float* __restrict__ gamma, const float* __restrict__ beta,
    const float* __restrict__ mean, const float* __restrict__ var,
    unsigned short* __restrict__ featsbf, unsigned short* __restrict__ hb, int N)
{
    int idx = blockIdx.x * blockDim.x + threadIdx.x;   // quad index
    if (idx >= N * (HH / 4)) return;
    int n = idx / (HH / 4), q = idx - n * (HH / 4);
    int f0 = 4 * q;
    f32x4 a  = *(const f32x4*)&agg[(size_t)n * HH + f0];
    f32x4 h  = *(const f32x4*)&hbuf[(size_t)n * HH + f0];
    f32x4 rt = *(const f32x4*)&root[f0];
    f32x4 gm = *(const f32x4*)&gamma[f0];
    f32x4 bt = *(const f32x4*)&beta[f0];
    f32x4 mn = *(const f32x4*)&mean[f0];
    f32x4 vr = *(const f32x4*)&var[f0];
    float di = 1.f / deg[n];
    float vv[4];
#pragma unroll
    for (int j = 0; j < 4; ++j) {
        float self = fmaxf(h[j] + rt[j], 0.f) * di;
        float v = fmaxf(a[j] + self, 0.f);
        vv[j] = (v - mn[j]) * rsqrtf(vr[j] + 1e-5f) * gm[j] + bt[j];
    }
    bfpack4 o;
    o.u[0] = pkbf2(vv[0], vv[1]);
    o.u[1] = pkbf2(vv[2], vv[3]);
    *(ubf16x4*)&featsbf[(size_t)n * CAT + f0] = o.v;
    *(ubf16x4*)&hb[(size_t)n * HH + f0] = o.v;
}

// ---------------- launch ----------------------------------------------------------
extern "C" void kernel_launch(void* const* d_in, const int* in_sizes, int n_in,
                              void* d_out, int out_size, void* d_ws, size_t ws_size,
                              hipStream_t stream)
{
    const float* x         = (const float*)d_in[0];
    const int*   eidx      = (const int*)d_in[1];
    const float* edge_attr = (const float*)d_in[2];
    const float* gcn_lin_w = (const float*)d_in[3];
    const float* gcn_lin_b = (const float*)d_in[4];
    const float* gcn_root  = (const float*)d_in[5];
    const float* gcn_bw1   = (const float*)d_in[6];
    const float* gcn_bb1   = (const float*)d_in[7];
    const float* gcn_bw2   = (const float*)d_in[8];
    const float* gcn_bb2   = (const float*)d_in[9];
    const float* gin_bw1   = (const float*)d_in[10];
    const float* gin_bb1   = (const float*)d_in[11];
    const float* gin_bw2   = (const float*)d_in[12];
    const float* gin_bb2   = (const float*)d_in[13];
    const float* gin_mw1   = (const float*)d_in[14];
    const float* gin_mb1   = (const float*)d_in[15];
    const float* gin_mw2   = (const float*)d_in[16];
    const float* gin_mb2   = (const float*)d_in[17];
    const float* gin_eps   = (const float*)d_in[18];
    const float* bn_gamma  = (const float*)d_in[19];
    const float* bn_beta   = (const float*)d_in[20];
    const float* bn_mean   = (const float*)d_in[21];
    const float* bn_var    = (const float*)d_in[22];
    const float* fc1_w     = (const float*)d_in[23];
    const float* fc1_b     = (const float*)d_in[24];
    const float* fc2_w     = (const float*)d_in[25];
    const float* fc2_b     = (const float*)d_in[26];
    float* out = (float*)d_out;

    const int N = in_sizes[0] / 128;   // 50000
    const int E = in_sizes[1] / 2;     // 800000
    const int* row = eidx;
    const int* col = eidx + E;

    // ws layout (bytes)
    char* ws = (char*)d_ws;
    float* deg        = (float*)(ws);                          // N f32
    float* dinv       = (float*)(ws + (size_t)256 * 1024);     // N f32
    int*   seg_start  = (int*)(ws + (size_t)512 * 1024);       // N+1
    int*   cursor     = (int*)(ws + (size_t)768 * 1024);       // N (also hist cnt)
    int*   bsum       = (int*)(ws + (size_t)1024 * 1024);      // 256
    int*   row_sorted = (int*)(ws + (size_t)1088 * 1024);      // E (3.2MB)
    unsigned short* ea_sorted = (unsigned short*)(ws + (size_t)8 * 1024 * 1024);    // E*16 bf16
    unsigned short* hb        = (unsigned short*)(ws + (size_t)34 * 1024 * 1024);   // N*96 bf16
    float* hbuf   = (float*)(ws + (size_t)44 * 1024 * 1024);   // N*96 f32
    float* agg    = (float*)(ws + (size_t)64 * 1024 * 1024);   // N*96 f32
    unsigned short* featsbf = (unsigned short*)(ws + (size_t)84 * 1024 * 1024);     // N*288 bf16
    unsigned short* r1bf    = (unsigned short*)(ws + (size_t)123 * 1024 * 1024);    // N*96 bf16

    const int ew_blocks = 1024;                     // 4 blocks/CU x 256 CU
    const int q_grid = (N * (HH / 4) + 255) / 256;
    const int gemm_grid = (N + 63) / 64;
    const int e_grid = (E + 255) / 256;
    const int n_grid = (N + 255) / 256;
    const int nchunks = (N + 255) / 256;

    // ---- degrees + CSR build ----
    init_kernel<<<n_grid, 256, 0, stream>>>(deg, cursor, N);
    count_kernel<<<e_grid, 256, 0, stream>>>(row, col, deg, cursor, E);
    scan1_kernel<<<nchunks, 256, 0, stream>>>(cursor, seg_start, bsum, N);
    scan2_kernel<<<1, 256, 0, stream>>>(bsum, nchunks);
    scan3_kernel<<<(N + 256) / 256, 256, 0, stream>>>(seg_start, bsum, cursor, deg, dinv, N, E);
    scatter_ea_kernel<<<e_grid, 256, 0, stream>>>(row, col, cursor, edge_attr,
                                                  row_sorted, ea_sorted, E);

    // ---- layer 0: GCN ----
    node_gemm<128, 96, 0, 3><<<gemm_grid, 256, 0, stream>>>(
        x, 128, gcn_lin_w, gcn_lin_b, hbuf, HH, hb, N);
    edge_kernel<true><<<ew_blocks, 256, 0, stream>>>(
        ea_sorted, row_sorted, seg_start,
        gcn_bw1, gcn_bb1, gcn_bw2, gcn_bb2, hb, dinv, agg, N);
    gcn_epilogue_kernel<<<q_grid, 256, 0, stream>>>(
        agg, hbuf, gcn_root, deg, bn_gamma, bn_beta, bn_mean, bn_var, featsbf, hb, N);

    // ---- layers 1..2: GIN (edge kernel + fused MLP) ----
    for (int i = 0; i < 2; ++i) {
        edge_kernel<false><<<ew_blocks, 256, 0, stream>>>(
            ea_sorted, row_sorted, seg_start,
            gin_bw1 + (size_t)i * EDGEF * HH, gin_bb1 + i * HH,
            gin_bw2 + (size_t)i * HH * HH, gin_bb2 + i * HH,
            hb, dinv, agg, N);
        gin_mlp<<<gemm_grid, 256, 0, stream>>>(
            hb, agg, gin_eps, i,
            gin_mw1 + (size_t)i * HH * HH, gin_mb1 + i * HH,
            gin_mw2 + (size_t)i * HH * HH, gin_mb2 + i * HH,
            bn_gamma + (i + 1) * HH, bn_beta + (i + 1) * HH,
            bn_mean + (i + 1) * HH, bn_var + (i + 1) * HH,
            featsbf, i + 1, hb, N);
    }

    // ---- head ----
    node_gemm<288, 96, 1, 1><<<gemm_grid, 256, 0, stream>>>(
        featsbf, CAT, fc1_w, fc1_b, r1bf, HH, nullptr, N);
    node_gemm<96, 64, 1, 0><<<gemm_grid, 256, 0, stream>>>(
        r1bf, HH, fc2_w, fc2_b, out, 64, nullptr, N);
}